// Round 11
// baseline (83.573 us; speedup 1.0000x reference)
//
#include <hip/hip_runtime.h>
#include <hip/hip_fp16.h>

#define CIN 32
#define COUT 64
#define NB 4
#define NPTS 32768
#define KNN 16

typedef unsigned short u16;
typedef unsigned char u8;
typedef float f2v __attribute__((ext_vector_type(2)));
typedef int i4v __attribute__((ext_vector_type(4)));
typedef unsigned int u4v __attribute__((ext_vector_type(4)));
typedef unsigned int u2v __attribute__((ext_vector_type(2)));

__device__ __forceinline__ u16 f2h(float f) {
  _Float16 h = (_Float16)f;
  u16 u; __builtin_memcpy(&u, &h, 2); return u;
}
__device__ __forceinline__ f2v h2_to_f2(unsigned int u) {
  _Float16 a, b;
  __builtin_memcpy(&a, (const char*)&u, 2);
  __builtin_memcpy(&b, ((const char*)&u) + 2, 2);
  return (f2v){(float)a, (float)b};
}

// Kernel 1: pure GEMM + store, all CACHED (NT store here was the R8
// regression: wave-strided 16B stores need L2 line-merging). lt fp16,
// et fp8 e4m3, both (B,N,64).
__global__ __launch_bounds__(256) void k1_gemm(
    const float* __restrict__ feat, const float* __restrict__ W1,
    const float* __restrict__ W2, u16* __restrict__ lt, u8* __restrict__ et) {
  const int bid = blockIdx.x;
  const int b = bid >> 9;
  const int n0 = (bid & 511) << 6;
  const int t = threadIdx.x;
  const int lane = t & 63;
  const int wchunk = __builtin_amdgcn_readfirstlane(t >> 6);
  const int n = n0 + lane;

  f2v fv[16];
  const float* fp = feat + (size_t)b * CIN * NPTS + n;
#pragma unroll
  for (int c2 = 0; c2 < 16; ++c2)
    fv[c2] = (f2v){fp[(size_t)(2 * c2) * NPTS], fp[(size_t)(2 * c2 + 1) * NPTS]};

  const int half = wchunk >> 1;        // 0 -> W1 (local fp16), 1 -> W2 (edge fp8)
  const int rbase = (wchunk & 1) * 32;
  const float* Wp = half ? W2 : W1;

  unsigned int pkh[16];
  unsigned int pk8[8];

#pragma unroll
  for (int oo = 0; oo < 32; oo += 4) {
    const float* w0 = Wp + (size_t)(rbase + oo) * CIN;
    const f2v* wr0 = reinterpret_cast<const f2v*>(w0);
    const f2v* wr1 = reinterpret_cast<const f2v*>(w0 + CIN);
    const f2v* wr2 = reinterpret_cast<const f2v*>(w0 + 2 * CIN);
    const f2v* wr3 = reinterpret_cast<const f2v*>(w0 + 3 * CIN);
    f2v p0 = (f2v)0.f, p1 = (f2v)0.f, p2 = (f2v)0.f, p3 = (f2v)0.f;
#pragma unroll
    for (int c2 = 0; c2 < 16; ++c2) {
      const f2v fc = fv[c2];
      p0 = __builtin_elementwise_fma(wr0[c2], fc, p0);
      p1 = __builtin_elementwise_fma(wr1[c2], fc, p1);
      p2 = __builtin_elementwise_fma(wr2[c2], fc, p2);
      p3 = __builtin_elementwise_fma(wr3[c2], fc, p3);
    }
    const float a0 = p0.x + p0.y, a1 = p1.x + p1.y;
    const float a2 = p2.x + p2.y, a3 = p3.x + p3.y;
    if (half == 0) {
      pkh[oo / 2]     = (unsigned)f2h(a0) | ((unsigned)f2h(a1) << 16);
      pkh[oo / 2 + 1] = (unsigned)f2h(a2) | ((unsigned)f2h(a3) << 16);
    } else {
      int u = 0;
      u = __builtin_amdgcn_cvt_pk_fp8_f32(a0, a1, u, false);
      u = __builtin_amdgcn_cvt_pk_fp8_f32(a2, a3, u, true);
      pk8[oo / 4] = (unsigned)u;
    }
  }
  if (half == 0) {
    u4v* dp = reinterpret_cast<u4v*>(lt + ((size_t)(b * NPTS + n)) * COUT + rbase);
#pragma unroll
    for (int q = 0; q < 4; ++q)
      dp[q] = (u4v){pkh[4 * q], pkh[4 * q + 1], pkh[4 * q + 2], pkh[4 * q + 3]};
  } else {
    u4v* dp = reinterpret_cast<u4v*>(et + ((size_t)(b * NPTS + n)) * COUT + rbase);
    dp[0] = (u4v){pk8[0], pk8[1], pk8[2], pk8[3]};
    dp[1] = (u4v){pk8[4], pk8[5], pk8[6], pk8[7]};
  }
}

// Kernel 2: fully decoupled waves — no LDS, no barriers, no launch-bounds
// cap. Thread = (n, 8 ch); R8's gather shape (16x 8B fp8, 8 cg lanes per
// 64B row). Output written directly with CACHED 4B stores: a wave-store
// covers 8 rows x 32B; sibling waves of the same block fill the other 32B
// of each 128B line ~concurrently -> L2 write-merge -> full-line writeback.
// Central half computed+stored while gathers are in flight.
// NT loads for touch-once knn/lt; gathers cached (et lives in L2).
__global__ void k2_gather(
    const u16* __restrict__ lt, const u8* __restrict__ et,
    const int* __restrict__ knn, const float* __restrict__ gamma,
    const float* __restrict__ beta, const float* __restrict__ mean,
    const float* __restrict__ var, float* __restrict__ out) {
  int bid = blockIdx.x;
  bid = (bid & 7) * 512 + (bid >> 3);   // 4096 % 8 == 0 -> bijective
  const int b = bid >> 10;              // 1024 blocks per batch
  const int n_blk = (bid & 1023) << 5;  // 32 n per block
  const int t = threadIdx.x;
  const int w = t >> 6;
  const int lane = t & 63;
  const int nn = lane >> 3;   // 0..7
  const int cg = lane & 7;    // 0..7
  const int ch = cg * 8;

  const int n = n_blk + w * 8 + nn;
  const size_t rowbase = (size_t)b * NPTS;

  // knn + local row (NT, touch-once)
  const i4v* kp = reinterpret_cast<const i4v*>(knn + (rowbase + n) * KNN);
  const i4v kv0 = __builtin_nontemporal_load(kp);
  const i4v kv1 = __builtin_nontemporal_load(kp + 1);
  const i4v kv2 = __builtin_nontemporal_load(kp + 2);
  const i4v kv3 = __builtin_nontemporal_load(kp + 3);
  const u4v lv = __builtin_nontemporal_load(
      reinterpret_cast<const u4v*>(lt + (rowbase + n) * COUT + ch));

  // issue all 16 gathers (8B fp8 each)
  const u8* etb = et + rowbase * COUT + ch;
  const int idx[16] = {kv0.x, kv0.y, kv0.z, kv0.w, kv1.x, kv1.y, kv1.z, kv1.w,
                       kv2.x, kv2.y, kv2.z, kv2.w, kv3.x, kv3.y, kv3.z, kv3.w};
  u2v e[16];
#pragma unroll
  for (int k = 0; k < 16; ++k)
    e[k] = *reinterpret_cast<const u2v*>(etb + ((size_t)(unsigned)idx[k] << 6));

  // BN constants + central half (computed + stored under gather latency)
  float* const outb = out + (size_t)b * 128 * NPTS + n;
  const unsigned int lw[4] = {lv.x, lv.y, lv.z, lv.w};
  const f2v zero = (f2v)0.f;
  f2v inv2[4], ttc[4];
#pragma unroll
  for (int i = 0; i < 4; ++i) {
    const f2v l = h2_to_f2(lw[i]);
    {  // central rows ch..ch+7 -> direct cached stores
      const int r0 = ch + 2 * i;
      const float iv0 = gamma[r0] * rsqrtf(var[r0] + 1e-5f);
      const float iv1 = gamma[r0 + 1] * rsqrtf(var[r0 + 1] + 1e-5f);
      const f2v iv = (f2v){iv0, iv1};
      const f2v sh = (f2v){beta[r0] - mean[r0] * iv0,
                           beta[r0 + 1] - mean[r0 + 1] * iv1};
      const f2v cen = __builtin_elementwise_max(
          __builtin_elementwise_fma(l, iv, sh), zero);
      outb[(size_t)r0 * NPTS] = cen.x;
      outb[(size_t)(r0 + 1) * NPTS] = cen.y;
    }
    {  // diff constants rows 64+ch..
      const int r0 = 64 + ch + 2 * i;
      const float iv0 = gamma[r0] * rsqrtf(var[r0] + 1e-5f);
      const float iv1 = gamma[r0 + 1] * rsqrtf(var[r0 + 1] + 1e-5f);
      inv2[i] = (f2v){iv0, iv1};
      const f2v sh = (f2v){beta[r0] - mean[r0] * iv0,
                           beta[r0 + 1] - mean[r0 + 1] * iv1};
      ttc[i] = sh - l * inv2[i];
    }
  }

  f2v acc[4] = {zero, zero, zero, zero};
#pragma unroll
  for (int k = 0; k < 16; ++k) {
    const f2v d0 = __builtin_amdgcn_cvt_pk_f32_fp8(e[k].x, false);
    const f2v d1 = __builtin_amdgcn_cvt_pk_f32_fp8(e[k].x, true);
    const f2v d2 = __builtin_amdgcn_cvt_pk_f32_fp8(e[k].y, false);
    const f2v d3 = __builtin_amdgcn_cvt_pk_f32_fp8(e[k].y, true);
    acc[0] += __builtin_elementwise_max(__builtin_elementwise_fma(d0, inv2[0], ttc[0]), zero);
    acc[1] += __builtin_elementwise_max(__builtin_elementwise_fma(d1, inv2[1], ttc[1]), zero);
    acc[2] += __builtin_elementwise_max(__builtin_elementwise_fma(d2, inv2[2], ttc[2]), zero);
    acc[3] += __builtin_elementwise_max(__builtin_elementwise_fma(d3, inv2[3], ttc[3]), zero);
  }
#pragma unroll
  for (int i = 0; i < 4; ++i) {
    const int r0 = 64 + ch + 2 * i;
    outb[(size_t)r0 * NPTS] = acc[i].x * 0.0625f;
    outb[(size_t)(r0 + 1) * NPTS] = acc[i].y * 0.0625f;
  }
}

extern "C" void kernel_launch(void* const* d_in, const int* in_sizes, int n_in,
                              void* d_out, int out_size, void* d_ws, size_t ws_size,
                              hipStream_t stream) {
  const float* feat  = (const float*)d_in[0];
  const int*   knn   = (const int*)d_in[1];
  const float* W1    = (const float*)d_in[2];
  const float* W2    = (const float*)d_in[3];
  const float* gamma = (const float*)d_in[4];
  const float* beta  = (const float*)d_in[5];
  const float* mean  = (const float*)d_in[6];
  const float* var   = (const float*)d_in[7];
  float* out = (float*)d_out;

  u16* lt = (u16*)d_ws;                           // (B,N,64) fp16 local, 16.8 MB
  u8* et = (u8*)(lt + (size_t)NB * NPTS * COUT);  // (B,N,64) fp8 edge, 8.4 MB

  k1_gemm<<<dim3(NB * NPTS / 64), 256, 0, stream>>>(feat, W1, W2, lt, et);
  k2_gather<<<dim3(NB * NPTS / 32), 256, 0, stream>>>(lt, et, knn, gamma, beta,
                                                      mean, var, out);
}

// Round 12
// 63.715 us; speedup vs baseline: 1.3117x; 1.3117x over previous
//
#include <hip/hip_runtime.h>
#include <hip/hip_fp16.h>

#define CIN 32
#define COUT 64
#define NB 4
#define NPTS 32768
#define KNN 16

typedef unsigned short u16;
typedef unsigned char u8;
typedef float f2v __attribute__((ext_vector_type(2)));
typedef float f4v __attribute__((ext_vector_type(4)));
typedef int i4v __attribute__((ext_vector_type(4)));
typedef unsigned int u4v __attribute__((ext_vector_type(4)));
typedef unsigned int u2v __attribute__((ext_vector_type(2)));

__device__ __forceinline__ u16 f2h(float f) {
  _Float16 h = (_Float16)f;
  u16 u; __builtin_memcpy(&u, &h, 2); return u;
}
__device__ __forceinline__ f2v h2_to_f2(unsigned int u) {
  _Float16 a, b;
  __builtin_memcpy(&a, (const char*)&u, 2);
  __builtin_memcpy(&b, ((const char*)&u) + 2, 2);
  return (f2v){(float)a, (float)b};
}

// Kernel 1 (R5 structure, proven): local = W1@feat (fp16 lt + central BN+ReLU
// fp32 out), edge = W2@feat (fp8 e4m3 et). v_pk_fma_f32 over CIN pairs,
// wave-uniform weight rows -> s_load. All loads/stores cached.
__global__ __launch_bounds__(256) void k1_gemm(
    const float* __restrict__ feat, const float* __restrict__ W1,
    const float* __restrict__ W2, const float* __restrict__ gamma,
    const float* __restrict__ beta, const float* __restrict__ mean,
    const float* __restrict__ var, u16* __restrict__ lt, u8* __restrict__ et,
    float* __restrict__ out) {
  const int bid = blockIdx.x;
  const int b = bid >> 9;
  const int n0 = (bid & 511) << 6;
  const int t = threadIdx.x;
  const int lane = t & 63;
  const int wchunk = __builtin_amdgcn_readfirstlane(t >> 6);
  const int n = n0 + lane;

  f2v fv[16];
  const float* fp = feat + (size_t)b * CIN * NPTS + n;
#pragma unroll
  for (int c2 = 0; c2 < 16; ++c2)
    fv[c2] = (f2v){fp[(size_t)(2 * c2) * NPTS], fp[(size_t)(2 * c2 + 1) * NPTS]};

  const int half = wchunk >> 1;        // 0 -> W1 (local fp16), 1 -> W2 (edge fp8)
  const int rbase = (wchunk & 1) * 32;
  const float* Wp = half ? W2 : W1;

  unsigned int pkh[16];
  unsigned int pk8[8];

#pragma unroll
  for (int oo = 0; oo < 32; oo += 4) {
    const float* w0 = Wp + (size_t)(rbase + oo) * CIN;
    const f2v* wr0 = reinterpret_cast<const f2v*>(w0);
    const f2v* wr1 = reinterpret_cast<const f2v*>(w0 + CIN);
    const f2v* wr2 = reinterpret_cast<const f2v*>(w0 + 2 * CIN);
    const f2v* wr3 = reinterpret_cast<const f2v*>(w0 + 3 * CIN);
    f2v p0 = (f2v)0.f, p1 = (f2v)0.f, p2 = (f2v)0.f, p3 = (f2v)0.f;
#pragma unroll
    for (int c2 = 0; c2 < 16; ++c2) {
      const f2v fc = fv[c2];
      p0 = __builtin_elementwise_fma(wr0[c2], fc, p0);
      p1 = __builtin_elementwise_fma(wr1[c2], fc, p1);
      p2 = __builtin_elementwise_fma(wr2[c2], fc, p2);
      p3 = __builtin_elementwise_fma(wr3[c2], fc, p3);
    }
    const float a0 = p0.x + p0.y, a1 = p1.x + p1.y;
    const float a2 = p2.x + p2.y, a3 = p3.x + p3.y;
    if (half == 0) {
      pkh[oo / 2]     = (unsigned)f2h(a0) | ((unsigned)f2h(a1) << 16);
      pkh[oo / 2 + 1] = (unsigned)f2h(a2) | ((unsigned)f2h(a3) << 16);
      const float acc[4] = {a0, a1, a2, a3};
#pragma unroll
      for (int i = 0; i < 4; ++i) {
        const int r = rbase + oo + i;
        const float iv = gamma[r] * rsqrtf(var[r] + 1e-5f);
        const float sh = beta[r] - mean[r] * iv;
        out[((size_t)b * 128 + r) * NPTS + n] = fmaxf(fmaf(acc[i], iv, sh), 0.f);
      }
    } else {
      int u = 0;
      u = __builtin_amdgcn_cvt_pk_fp8_f32(a0, a1, u, false);
      u = __builtin_amdgcn_cvt_pk_fp8_f32(a2, a3, u, true);
      pk8[oo / 4] = (unsigned)u;
    }
  }
  if (half == 0) {
    u4v* dp = reinterpret_cast<u4v*>(lt + ((size_t)(b * NPTS + n)) * COUT + rbase);
#pragma unroll
    for (int q = 0; q < 4; ++q)
      dp[q] = (u4v){pkh[4 * q], pkh[4 * q + 1], pkh[4 * q + 2], pkh[4 * q + 3]};
  } else {
    u4v* dp = reinterpret_cast<u4v*>(et + ((size_t)(b * NPTS + n)) * COUT + rbase);
    dp[0] = (u4v){pk8[0], pk8[1], pk8[2], pk8[3]};
    dp[1] = (u4v){pk8[4], pk8[5], pk8[6], pk8[7]};
  }
}

// Kernel 2 (R5 gather core, 512-thread blocks): diff half only. lane =
// nn*8+cg: thread owns (n = n_blk + w*8 + nn, channels 8cg..8cg+7); 16x 8B
// fp8 gathers, 8 cg lanes cover one 64B row. 8 waves/block = 64 n/block,
// 2048 blocks -> half the launch churn of R5, 2x resident waves/block.
// NT loads for touch-once knn/lt; gathers + out stores cached (et in L2;
// staged f4v writes need line-merge). XCD-swizzled grid.
__global__ __launch_bounds__(512) void k2_gather(
    const u16* __restrict__ lt, const u8* __restrict__ et,
    const int* __restrict__ knn, const float* __restrict__ gamma,
    const float* __restrict__ beta, const float* __restrict__ mean,
    const float* __restrict__ var, float* __restrict__ out) {
  __shared__ float obuf[64 * 65];
  int bid = blockIdx.x;
  bid = (bid & 7) * 256 + (bid >> 3);   // 2048 % 8 == 0 -> bijective
  const int b = bid >> 9;               // 512 blocks per batch
  const int n_blk = (bid & 511) << 6;   // 64 n per block
  const int t = threadIdx.x;
  const int w = t >> 6;                 // 0..7
  const int lane = t & 63;
  const int nn = lane >> 3;   // 0..7
  const int cg = lane & 7;    // 0..7
  const int ch = cg * 8;

  const int col = w * 8 + nn;           // 0..63
  const int n = n_blk + col;
  const size_t rowbase = (size_t)b * NPTS;

  // knn + local row (NT, touch-once)
  const i4v* kp = reinterpret_cast<const i4v*>(knn + (rowbase + n) * KNN);
  const i4v kv0 = __builtin_nontemporal_load(kp);
  const i4v kv1 = __builtin_nontemporal_load(kp + 1);
  const i4v kv2 = __builtin_nontemporal_load(kp + 2);
  const i4v kv3 = __builtin_nontemporal_load(kp + 3);
  const u4v lv = __builtin_nontemporal_load(
      reinterpret_cast<const u4v*>(lt + (rowbase + n) * COUT + ch));

  // issue all 16 gathers (8B fp8 each), cached
  const u8* etb = et + rowbase * COUT + ch;
  const int idx[16] = {kv0.x, kv0.y, kv0.z, kv0.w, kv1.x, kv1.y, kv1.z, kv1.w,
                       kv2.x, kv2.y, kv2.z, kv2.w, kv3.x, kv3.y, kv3.z, kv3.w};
  u2v e[16];
#pragma unroll
  for (int k = 0; k < 16; ++k)
    e[k] = *reinterpret_cast<const u2v*>(etb + ((size_t)(unsigned)idx[k] << 6));

  // BN constants + tt (VALU under gather latency)
  const unsigned int lw[4] = {lv.x, lv.y, lv.z, lv.w};
  const f2v zero = (f2v)0.f;
  f2v inv2[4], ttc[4];
#pragma unroll
  for (int i = 0; i < 4; ++i) {
    const int r0 = 64 + ch + 2 * i;
    const float iv0 = gamma[r0] * rsqrtf(var[r0] + 1e-5f);
    const float iv1 = gamma[r0 + 1] * rsqrtf(var[r0 + 1] + 1e-5f);
    inv2[i] = (f2v){iv0, iv1};
    const f2v sh = (f2v){beta[r0] - mean[r0] * iv0,
                         beta[r0 + 1] - mean[r0 + 1] * iv1};
    ttc[i] = sh - h2_to_f2(lw[i]) * inv2[i];
  }

  f2v acc[4] = {zero, zero, zero, zero};
#pragma unroll
  for (int k = 0; k < 16; ++k) {
    const f2v d0 = __builtin_amdgcn_cvt_pk_f32_fp8(e[k].x, false);
    const f2v d1 = __builtin_amdgcn_cvt_pk_f32_fp8(e[k].x, true);
    const f2v d2 = __builtin_amdgcn_cvt_pk_f32_fp8(e[k].y, false);
    const f2v d3 = __builtin_amdgcn_cvt_pk_f32_fp8(e[k].y, true);
    acc[0] += __builtin_elementwise_max(__builtin_elementwise_fma(d0, inv2[0], ttc[0]), zero);
    acc[1] += __builtin_elementwise_max(__builtin_elementwise_fma(d1, inv2[1], ttc[1]), zero);
    acc[2] += __builtin_elementwise_max(__builtin_elementwise_fma(d2, inv2[2], ttc[2]), zero);
    acc[3] += __builtin_elementwise_max(__builtin_elementwise_fma(d3, inv2[3], ttc[3]), zero);
  }
#pragma unroll
  for (int i = 0; i < 4; ++i) {
    obuf[(ch + 2 * i) * 65 + col] = acc[i].x * 0.0625f;
    obuf[(ch + 2 * i + 1) * 65 + col] = acc[i].y * 0.0625f;
  }
  __syncthreads();
  // write 64 diff rows x 64 n, coalesced f4v cached stores
#pragma unroll
  for (int r = 0; r < 2; ++r) {
    const int c = r * 32 + (t >> 4);
    const int n4 = (t & 15) * 4;
    const f4v v = {obuf[c * 65 + n4], obuf[c * 65 + n4 + 1],
                   obuf[c * 65 + n4 + 2], obuf[c * 65 + n4 + 3]};
    *reinterpret_cast<f4v*>(out + ((size_t)b * 128 + 64 + c) * NPTS + n_blk + n4) = v;
  }
}

extern "C" void kernel_launch(void* const* d_in, const int* in_sizes, int n_in,
                              void* d_out, int out_size, void* d_ws, size_t ws_size,
                              hipStream_t stream) {
  const float* feat  = (const float*)d_in[0];
  const int*   knn   = (const int*)d_in[1];
  const float* W1    = (const float*)d_in[2];
  const float* W2    = (const float*)d_in[3];
  const float* gamma = (const float*)d_in[4];
  const float* beta  = (const float*)d_in[5];
  const float* mean  = (const float*)d_in[6];
  const float* var   = (const float*)d_in[7];
  float* out = (float*)d_out;

  u16* lt = (u16*)d_ws;                           // (B,N,64) fp16 local, 16.8 MB
  u8* et = (u8*)(lt + (size_t)NB * NPTS * COUT);  // (B,N,64) fp8 edge, 8.4 MB

  k1_gemm<<<dim3(NB * NPTS / 64), 256, 0, stream>>>(feat, W1, W2, gamma, beta,
                                                    mean, var, lt, et, out);
  k2_gather<<<dim3(NB * NPTS / 64), 512, 0, stream>>>(lt, et, knn, gamma, beta,
                                                      mean, var, out);
}